// Round 6
// baseline (1377.056 us; speedup 1.0000x reference)
//
#include <hip/hip_runtime.h>

#define DMM 768
#define DFF 3072
#define NH  12
#define HD  64
#define SQ  197
#define BA  64
#define NDD 732
#define MROWS (BA*SQ)   // 12608
#define MPAD  12672     // 99*128
#define KS2   72        // Ks LDS stride (16B-aligned rows, free 2-way banking)
#define PPS   232       // P LDS stride (232: PV-side ds_read_b128 conflict-free)
#define VTS   232       // Vt read stride
#define QS    2304      // fused QKV row stride
#define BIASN (NH*208*208)

typedef unsigned short u16;
typedef __bf16 bf16x8 __attribute__((ext_vector_type(8)));
typedef float  f32x4  __attribute__((ext_vector_type(4)));
typedef unsigned short us8 __attribute__((ext_vector_type(8)));

__device__ __forceinline__ u16 f2b(float f) {
    unsigned v; __builtin_memcpy(&v, &f, 4);
    unsigned r = v + 0x7FFFu + ((v >> 16) & 1u);
    return (u16)(r >> 16);
}
__device__ __forceinline__ float gelu_exact(float x) {
    return 0.5f * x * (1.0f + erff(x * 0.70710678118654752f));
}
__device__ __forceinline__ void gload16(const u16* g, u16* l) {
    __builtin_amdgcn_global_load_lds(
        (const __attribute__((address_space(1))) unsigned int*)(g),
        (__attribute__((address_space(3))) unsigned int*)(l), 16, 0, 0);
}
__device__ __forceinline__ void hard_barrier() {
    asm volatile("s_waitcnt lgkmcnt(0)" ::: "memory");
    __builtin_amdgcn_s_barrier();
}

// ------ fused patch embed + layer-0 layernorm: row-per-block --------------
__global__ __launch_bounds__(256) void patchln_k(
    const float* __restrict__ x, const float* __restrict__ cls,
    const float* __restrict__ g, const float* __restrict__ b,
    float* __restrict__ h, u16* __restrict__ hn) {
    int row = blockIdx.x, tid = threadIdx.x;
    float x0 = 0.0f, x1 = 0.0f, x2 = 0.0f;
    if (row < MROWS) {
        int bb = row / SQ, s = row % SQ;
        const float* src = (s == 0) ? cls : &x[((long)bb * 196 + (s - 1)) * DMM];
        x0 = src[tid]; x1 = src[tid + 256]; x2 = src[tid + 512];
    }
    float* hr = h + (long)row * DMM;
    hr[tid] = x0; hr[tid + 256] = x1; hr[tid + 512] = x2;
    float s = x0 + x1 + x2, sq = x0 * x0 + x1 * x1 + x2 * x2;
    #pragma unroll
    for (int m = 32; m > 0; m >>= 1) {
        s  += __shfl_xor(s,  m, 64);
        sq += __shfl_xor(sq, m, 64);
    }
    __shared__ float ls[4], lq[4];
    int w = tid >> 6;
    if ((tid & 63) == 0) { ls[w] = s; lq[w] = sq; }
    __syncthreads();
    s  = ls[0] + ls[1] + ls[2] + ls[3];
    sq = lq[0] + lq[1] + lq[2] + lq[3];
    float mean = s * (1.0f / DMM);
    float var  = fmaxf(sq * (1.0f / DMM) - mean * mean, 0.0f);
    float rs = rsqrtf(var + 1e-12f);
    u16* hnr = hn + (long)row * DMM;
    hnr[tid]       = f2b((x0 - mean) * rs * g[tid]       + b[tid]);
    hnr[tid + 256] = f2b((x1 - mean) * rs * g[tid + 256] + b[tid + 256]);
    hnr[tid + 512] = f2b((x2 - mean) * rs * g[tid + 512] + b[tid + 512]);
}

// ------- fused transpose+cast: in fp32 [K][N] -> out bf16 [N][K] ----------
__global__ __launch_bounds__(256) void tcast_k(const float* __restrict__ in,
                                               u16* __restrict__ out,
                                               int Kd, int Nd) {
    __shared__ float t[32][33];
    int k0 = blockIdx.x * 32, n0 = blockIdx.y * 32;
    int tx = threadIdx.x & 31, ty = threadIdx.x >> 5;   // ty 0..7
    #pragma unroll
    for (int i = 0; i < 4; ++i)
        t[tx][ty + 8 * i] = in[(long)(k0 + ty + 8 * i) * Nd + n0 + tx];
    __syncthreads();
    #pragma unroll
    for (int i = 0; i < 4; ++i)
        out[(long)(n0 + ty + 8 * i) * Kd + k0 + tx] = f2b(t[ty + 8 * i][tx]);
}

// ------- 4x batched 768x768 transpose+cast (one launch per layer) ---------
__global__ __launch_bounds__(256) void tcast4_k(
    const float* __restrict__ s0, const float* __restrict__ s1,
    const float* __restrict__ s2, const float* __restrict__ s3,
    u16* __restrict__ d0, u16* __restrict__ d1,
    u16* __restrict__ d2, u16* __restrict__ d3) {
    __shared__ float t[32][33];
    int z = blockIdx.z;
    const float* in = (z == 0) ? s0 : (z == 1) ? s1 : (z == 2) ? s2 : s3;
    u16* out = (z == 0) ? d0 : (z == 1) ? d1 : (z == 2) ? d2 : d3;
    int k0 = blockIdx.x * 32, n0 = blockIdx.y * 32;
    int tx = threadIdx.x & 31, ty = threadIdx.x >> 5;
    #pragma unroll
    for (int i = 0; i < 4; ++i)
        t[tx][ty + 8 * i] = in[(long)(k0 + ty + 8 * i) * DMM + n0 + tx];
    __syncthreads();
    #pragma unroll
    for (int i = 0; i < 4; ++i)
        out[(long)(n0 + ty + 8 * i) * DMM + k0 + tx] = f2b(t[ty + 8 * i][tx]);
}

// ---------------- layernorm: h fp32 -> hn bf16 ----------------------------
__global__ __launch_bounds__(256) void ln_k(const float* __restrict__ h,
                                            const float* __restrict__ g,
                                            const float* __restrict__ b,
                                            u16* __restrict__ hn) {
    int row = blockIdx.x, tid = threadIdx.x;
    const float* hr = h + (long)row * DMM;
    float x0 = hr[tid], x1 = hr[tid + 256], x2 = hr[tid + 512];
    float s = x0 + x1 + x2, sq = x0 * x0 + x1 * x1 + x2 * x2;
    #pragma unroll
    for (int m = 32; m > 0; m >>= 1) {
        s  += __shfl_xor(s,  m, 64);
        sq += __shfl_xor(sq, m, 64);
    }
    __shared__ float ls[4], lq[4];
    int w = tid >> 6;
    if ((tid & 63) == 0) { ls[w] = s; lq[w] = sq; }
    __syncthreads();
    s  = ls[0] + ls[1] + ls[2] + ls[3];
    sq = lq[0] + lq[1] + lq[2] + lq[3];
    float mean = s * (1.0f / DMM);
    float var  = fmaxf(sq * (1.0f / DMM) - mean * mean, 0.0f);
    float rs = rsqrtf(var + 1e-12f);
    u16* hnr = hn + (long)row * DMM;
    hnr[tid]       = f2b((x0 - mean) * rs * g[tid]       + b[tid]);
    hnr[tid + 256] = f2b((x1 - mean) * rs * g[tid + 256] + b[tid + 256]);
    hnr[tid + 512] = f2b((x2 - mean) * rs * g[tid + 512] + b[tid + 512]);
}

// ---------------- GEMM: C[M][N] = A[M][K] @ B  (B given as BT[N][K]) ------
// r2/r5 structure (empirically best across dist-1/dist-2/8-phase variants).
template <int EPI>
__global__ __launch_bounds__(256) void gemm_bt(
    const u16* __restrict__ A, const u16* __restrict__ BT,
    const float* __restrict__ bias, u16* __restrict__ outB,
    float* __restrict__ hio, const float* __restrict__ lam,
    float* __restrict__ hout, int K, int N) {
    __shared__ __align__(16) u16 pool[16384];
    int tid = threadIdx.x;
    int w = tid >> 6, lane = tid & 63;
    int wr = w >> 1, wc = w & 1;
    int m16 = lane & 15;
    int kq  = (lane >> 4) * 8;
    int kq4 = (lane >> 4) * 4;

    int nwg = gridDim.x, bid = blockIdx.x;
    int qd = nwg >> 3, rm = nwg & 7;
    int xcd = bid & 7, seq = bid >> 3;
    int wg = (xcd < rm ? xcd * (qd + 1) : rm * (qd + 1) + (xcd - rm) * qd) + seq;
    int ntn = N >> 7;
    long m0 = (long)(wg / ntn) * 128;
    long n0 = (long)(wg % ntn) * 128;

    f32x4 acc[4][4] = {};

    int row_a = tid >> 2;
    int col_a = (tid & 3) * 8;
    const u16* gA0 = &A[(m0 + row_a) * (long)K + col_a];
    const u16* gA1 = &A[(m0 + 64 + row_a) * (long)K + col_a];
    const u16* gB0 = &BT[(n0 + row_a) * (long)K + col_a];
    const u16* gB1 = &BT[(n0 + 64 + row_a) * (long)K + col_a];
    int wo = w * 512;

    u16* const b0 = pool;
    u16* const b1 = pool + 8192;

    auto stage = [&](int k, u16* buf) {
        int k0 = k << 5;
        gload16(gA0 + k0, buf + wo);
        gload16(gA1 + k0, buf + 2048 + wo);
        gload16(gB0 + k0, buf + 4096 + wo);
        gload16(gB1 + k0, buf + 6144 + wo);
    };
    auto compute = [&](const u16* buf) {
        bf16x8 af[4], bf[4];
        #pragma unroll
        for (int i = 0; i < 4; ++i)
            af[i] = *(const bf16x8*)&buf[(wr * 64 + i * 16 + m16) * 32 + kq];
        #pragma unroll
        for (int j = 0; j < 4; ++j)
            bf[j] = *(const bf16x8*)&buf[4096 + (wc * 64 + j * 16 + m16) * 32 + kq];
        #pragma unroll
        for (int i = 0; i < 4; ++i)
            #pragma unroll
            for (int j = 0; j < 4; ++j)
                acc[i][j] = __builtin_amdgcn_mfma_f32_16x16x32_bf16(
                    af[i], bf[j], acc[i][j], 0, 0, 0);
    };

    const int nsteps = K >> 5;
    stage(0, b0);
    for (int ks = 0; ks < nsteps - 2; ks += 2) {
        stage(ks + 1, b1);
        asm volatile("s_waitcnt vmcnt(4)" ::: "memory");
        __builtin_amdgcn_s_barrier();
        compute(b0);
        hard_barrier();
        stage(ks + 2, b0);
        asm volatile("s_waitcnt vmcnt(4)" ::: "memory");
        __builtin_amdgcn_s_barrier();
        compute(b1);
        hard_barrier();
    }
    stage(nsteps - 1, b1);
    asm volatile("s_waitcnt vmcnt(4)" ::: "memory");
    __builtin_amdgcn_s_barrier();
    compute(b0);
    hard_barrier();
    asm volatile("s_waitcnt vmcnt(0)" ::: "memory");
    __builtin_amdgcn_s_barrier();
    compute(b1);

    // ---- epilogue: stage C tile through LDS (fp32), coalesced global I/O --
    hard_barrier();
    float* Cs = (float*)pool;              // [64][128] fp32 = 32768 B
    float bcol[4];
    #pragma unroll
    for (int j = 0; j < 4; ++j)
        bcol[j] = bias ? bias[n0 + wc * 64 + j * 16 + m16] : 0.0f;
    int et4 = tid * 4;
    int colr = et4 & 127;
    f32x4 lam4 = {};
    if (EPI == 2) lam4 = *(const f32x4*)&lam[n0 + colr];

    #pragma unroll
    for (int p = 0; p < 2; ++p) {
        if (p) hard_barrier();
        if (wr == p) {
            #pragma unroll
            for (int i = 0; i < 4; ++i)
                #pragma unroll
                for (int j = 0; j < 4; ++j)
                    #pragma unroll
                    for (int r = 0; r < 4; ++r)
                        Cs[(i * 16 + kq4 + r) * 128 + wc * 64 + j * 16 + m16] =
                            acc[i][j][r] + bcol[j];
        }
        hard_barrier();
        #pragma unroll
        for (int k = 0; k < 8; ++k) {
            int e0 = k * 1024 + et4;
            int row = e0 >> 7;
            f32x4 v = *(const f32x4*)&Cs[row * 128 + colr];
            long grow = m0 + p * 64 + row;
            long gi = grow * (long)N + n0 + colr;
            if (EPI == 0) {
                uint2 o;
                o.x = (unsigned)f2b(v[0]) | ((unsigned)f2b(v[1]) << 16);
                o.y = (unsigned)f2b(v[2]) | ((unsigned)f2b(v[3]) << 16);
                *(uint2*)&outB[gi] = o;
            } else if (EPI == 1) {
                uint2 o;
                o.x = (unsigned)f2b(gelu_exact(v[0])) | ((unsigned)f2b(gelu_exact(v[1])) << 16);
                o.y = (unsigned)f2b(gelu_exact(v[2])) | ((unsigned)f2b(gelu_exact(v[3])) << 16);
                *(uint2*)&outB[gi] = o;
            } else {
                f32x4 hv = *(f32x4*)&hio[gi];
                #pragma unroll
                for (int t = 0; t < 4; ++t) hv[t] += v[t] * lam4[t];
                *(f32x4*)&hio[gi] = hv;
                if (hout != nullptr && grow < MROWS)
                    *(f32x4*)&hout[gi] = hv;
            }
        }
    }
}

// ---------------- relative position bias index ----------------------------
__device__ __forceinline__ int relidx(int q, int k) {
    if (q == 0 && k == 0) return NDD - 1;
    if (k == 0) return NDD - 2;
    if (q == 0) return NDD - 3;
    int a = q - 1, c = k - 1;
    int dh = a / 14 - c / 14 + 13;
    int dw = a % 14 - c % 14 + 13;
    return dh * 27 + dw;
}

// -- precompute bias[h][208][208] fp32 + fused bqkv concat (one launch) ----
__global__ void bias_k(const float* __restrict__ rel, float* __restrict__ bias,
                       const float* __restrict__ bq, const float* __restrict__ bv,
                       float* __restrict__ bqkv) {
    int idx = blockIdx.x * 256 + threadIdx.x;
    if (idx < BIASN) {
        int hh = idx / (208 * 208);
        int r = (idx / 208) % 208, c = idx % 208;
        float v = 0.0f;
        if (r < SQ && c < SQ) v = rel[relidx(r, c) * NH + hh];
        bias[idx] = v;
    } else {
        int i = idx - BIASN;
        if (i < QS)
            bqkv[i] = (i < 768) ? bq[i] : ((i < 1536) ? 0.0f : bv[i - 1536]);
    }
}

// ======== fused attention: S = QK^T*scale + bias, softmax, ctx = P@V ======
// P never leaves LDS (tile->wave map identical on both sides: t = w; t += 4).
// Dynamic LDS: Ks[208*KS2] (29952 B, reused for Vt 64*VTS = 29696 B)
//            + Ps[208*PPS] (96512 B) = 126464 B -> 1 block/CU.
// PPS=232: PV-side 16-lane ds_read_b128 row-stride 464 B -> 2 lanes/bank
// group (free); 224 would be 8-way.
__global__ __launch_bounds__(256) void attn_k(
    const u16* __restrict__ QKV, const float* __restrict__ bias,
    u16* __restrict__ ctx) {
    extern __shared__ __align__(16) u16 apool[];
    u16* Ks = apool;                 // 14976 u16
    u16* Ps = apool + 14976;         // 48256 u16
    int bh = blockIdx.x;
    int b = bh / NH, hh = bh % NH;
    int tid = threadIdx.x, w = tid >> 6, lane = tid & 63;
    long base = ((long)b * SQ) * QS + hh * HD;
    const u16* Qp = QKV;
    const u16* Kp = QKV + 768;
    // zero P pad cols 208..223 (read by ks=6 in PV; rows all written below)
    for (int idx = tid; idx < 208 * 16; idx += 256)
        Ps[(idx >> 4) * PPS + 208 + (idx & 15)] = 0;
    // stage K rows 0..207 (zeros beyond 196)
    for (int idx = tid; idx < 208 * 8; idx += 256) {
        int row = idx >> 3, dg = (idx & 7) * 8;
        us8 kv = {};
        if (row < SQ) kv = *(const us8*)&Kp[base + (long)row * QS + dg];
        *(us8*)&Ks[row * KS2 + dg] = kv;
    }
    __syncthreads();
    int m16 = lane & 15, quad = lane >> 4;
    int kq8 = quad * 8, q4 = quad * 4;
    const float* bh_bias = bias + (long)hh * 208 * 208;
    for (int t = w; t < 13; t += 4) {
        int m0 = t * 16;
        int qrow = m0 + m16; if (qrow > SQ - 1) qrow = SQ - 1;   // clamp pad rows
        bf16x8 a0 = *(const bf16x8*)&Qp[base + (long)qrow * QS + kq8];
        bf16x8 a1 = *(const bf16x8*)&Qp[base + (long)qrow * QS + 32 + kq8];
        f32x4 sc[13];
        #pragma unroll
        for (int n = 0; n < 13; ++n) {
            bf16x8 b0 = *(const bf16x8*)&Ks[(n * 16 + m16) * KS2 + kq8];
            bf16x8 b1 = *(const bf16x8*)&Ks[(n * 16 + m16) * KS2 + 32 + kq8];
            f32x4 z = {};
            z = __builtin_amdgcn_mfma_f32_16x16x32_bf16(a0, b0, z, 0, 0, 0);
            z = __builtin_amdgcn_mfma_f32_16x16x32_bf16(a1, b1, z, 0, 0, 0);
            sc[n] = z;
        }
        float mx[4] = {-3e38f, -3e38f, -3e38f, -3e38f};
        #pragma unroll
        for (int n = 0; n < 13; ++n) {
            int col = n * 16 + m16;
            bool valid = col < SQ;
            #pragma unroll
            for (int r = 0; r < 4; ++r) {
                float v = sc[n][r] * 0.125f + bh_bias[(m0 + q4 + r) * 208 + col];
                v = valid ? v : -3e38f;
                sc[n][r] = v;
                mx[r] = fmaxf(mx[r], v);
            }
        }
        #pragma unroll
        for (int r = 0; r < 4; ++r)
            #pragma unroll
            for (int msk = 1; msk < 16; msk <<= 1)
                mx[r] = fmaxf(mx[r], __shfl_xor(mx[r], msk, 64));
        float sum[4] = {0, 0, 0, 0};
        #pragma unroll
        for (int n = 0; n < 13; ++n)
            #pragma unroll
            for (int r = 0; r < 4; ++r) {
                float e = __expf(sc[n][r] - mx[r]);   // underflows to 0 when masked
                sc[n][r] = e;
                sum[r] += e;
            }
        #pragma unroll
        for (int r = 0; r < 4; ++r)
            #pragma unroll
            for (int msk = 1; msk < 16; msk <<= 1)
                sum[r] += __shfl_xor(sum[r], msk, 64);
        float inv[4];
        #pragma unroll
        for (int r = 0; r < 4; ++r) inv[r] = 1.0f / sum[r];
        #pragma unroll
        for (int n = 0; n < 13; ++n) {
            int col = n * 16 + m16;
            #pragma unroll
            for (int r = 0; r < 4; ++r)
                Ps[(m0 + q4 + r) * PPS + col] = f2b(sc[n][r] * inv[r]);
        }
    }
    __syncthreads();                 // all waves done with Ks reads + P writes
    // stage V (transposed) into the dead Ks region: Vt[d][k], zeros k >= 197
    u16* Vt = Ks;
    long vbase = base + 1536;
    for (int idx = tid; idx < 224 * 8; idx += 256) {
        int row = idx >> 3, dg = (idx & 7) * 8;   // row = k index
        us8 vv = {};
        if (row < SQ) vv = *(const us8*)&QKV[vbase + (long)row * QS + dg];
        #pragma unroll
        for (int j = 0; j < 8; ++j) Vt[(dg + j) * VTS + row] = vv[j];
    }
    __syncthreads();
    long basec = ((long)b * SQ) * DMM + hh * HD;
    for (int t = w; t < 13; t += 4) {
        int m0 = t * 16;
        f32x4 co[4] = {};
        #pragma unroll
        for (int ks = 0; ks < 7; ++ks) {
            bf16x8 ap = *(const bf16x8*)&Ps[(m0 + m16) * PPS + ks * 32 + kq8];
            #pragma unroll
            for (int n = 0; n < 4; ++n) {
                bf16x8 bv = *(const bf16x8*)&Vt[(n * 16 + m16) * VTS + ks * 32 + kq8];
                co[n] = __builtin_amdgcn_mfma_f32_16x16x32_bf16(ap, bv, co[n], 0, 0, 0);
            }
        }
        #pragma unroll
        for (int n = 0; n < 4; ++n) {
            int col = n * 16 + m16;
            #pragma unroll
            for (int r = 0; r < 4; ++r) {
                int qr = m0 + q4 + r;
                if (qr < SQ) ctx[basec + (long)qr * DMM + col] = f2b(co[n][r]);
            }
        }
    }
}

// ---------------- host-side orchestration ---------------------------------
extern "C" void kernel_launch(void* const* d_in, const int* in_sizes, int n_in,
                              void* d_out, int out_size, void* d_ws, size_t ws_size,
                              hipStream_t stream) {
    const float* x    = (const float*)d_in[0];
    const float* cls  = (const float*)d_in[1];
    const float* g1   = (const float*)d_in[2];
    const float* b1   = (const float*)d_in[3];
    const float* Wq   = (const float*)d_in[4];
    const float* bq   = (const float*)d_in[5];
    const float* Wk   = (const float*)d_in[6];
    const float* Wv   = (const float*)d_in[7];
    const float* bv   = (const float*)d_in[8];
    const float* rel  = (const float*)d_in[9];
    const float* Wo   = (const float*)d_in[10];
    const float* bo   = (const float*)d_in[11];
    const float* lam1 = (const float*)d_in[12];
    const float* g2   = (const float*)d_in[13];
    const float* b2   = (const float*)d_in[14];
    const float* Wi   = (const float*)d_in[15];
    const float* bi   = (const float*)d_in[16];
    const float* Wmo  = (const float*)d_in[17];
    const float* bmo  = (const float*)d_in[18];
    const float* lam2 = (const float*)d_in[19];

    char* p = (char*)d_ws;
    auto alloc = [&](size_t bytes) -> void* {
        void* r = (void*)p;
        p += (bytes + 255) & ~(size_t)255;
        return r;
    };
    float* h     = (float*)alloc((size_t)MPAD * DMM * 4);
    u16*   hn    = (u16*)alloc((size_t)MPAD * DMM * 2);   // also reused as ctx
    u16*   qkvb  = (u16*)alloc((size_t)MPAD * QS * 2);    // fused Q|K|V
    u16*   ffh   = (u16*)alloc((size_t)MPAD * DFF * 2);
    u16*   WqkvT = (u16*)alloc((size_t)QS * DMM * 2);     // [2304][768]
    u16*   WoT   = (u16*)alloc((size_t)DMM * DMM * 2);
    u16*   WiT   = (u16*)alloc((size_t)DMM * DFF * 2);
    u16*   WmoT  = (u16*)alloc((size_t)DFF * DMM * 2);
    float* biasb = (float*)alloc((size_t)NH * 208 * 208 * 4);
    float* bqkv  = (float*)alloc((size_t)QS * 4);
    u16*   ctxb  = hn;   // alias: hn dead after QKV GEMM

    dim3 tg4(DMM / 32, DMM / 32, 4);
    dim3 tg2(DMM / 32, DFF / 32);
    dim3 tg3(DFF / 32, DMM / 32);
    int gqkv = (MPAD / 128) * (QS / 128);    // 99*18 = 1782
    int g6   = (MPAD / 128) * (DMM / 128);   // 99*6  = 594
    int g24  = (MPAD / 128) * (DFF / 128);   // 99*24 = 2376
    const size_t ALDS = (size_t)(208 * KS2 + 208 * PPS) * 2;   // 126464 B

    // fused patch embed + layer-0 LN
    patchln_k<<<MPAD, 256, 0, stream>>>(x, cls, g1, b1, h, hn);

    for (int i = 0; i < 3; ++i) {
        size_t wofs  = (size_t)i * DMM * DMM;
        size_t wofs2 = (size_t)i * DMM * DFF;
        tcast4_k<<<tg4, 256, 0, stream>>>(Wq + wofs, Wk + wofs, Wv + wofs, Wo + wofs,
                                          WqkvT, WqkvT + 768 * DMM,
                                          WqkvT + 2 * 768 * DMM, WoT);
        tcast_k<<<tg2, 256, 0, stream>>>(Wi + wofs2, WiT, DMM, DFF);
        tcast_k<<<tg3, 256, 0, stream>>>(Wmo + wofs2, WmoT, DFF, DMM);
        bias_k<<<(BIASN + QS + 255) / 256, 256, 0, stream>>>(
            rel + (size_t)i * NDD * NH, biasb, bq + i * DMM, bv + i * DMM, bqkv);

        if (i > 0)
            ln_k<<<MPAD, 256, 0, stream>>>(h, g1 + i * DMM, b1 + i * DMM, hn);
        gemm_bt<0><<<gqkv, 256, 0, stream>>>(hn, WqkvT, bqkv, qkvb, nullptr, nullptr, nullptr, DMM, QS);
        attn_k<<<BA * NH, 256, ALDS, stream>>>(qkvb, biasb, ctxb);
        gemm_bt<2><<<g6, 256, 0, stream>>>(ctxb, WoT, bo + i * DMM, nullptr, h, lam1 + i * DMM, nullptr, DMM, DMM);
        ln_k<<<MPAD, 256, 0, stream>>>(h, g2 + i * DMM, b2 + i * DMM, hn);
        gemm_bt<1><<<g24, 256, 0, stream>>>(hn, WiT, bi + i * DFF, ffh, nullptr, nullptr, nullptr, DMM, DFF);
        gemm_bt<2><<<g6, 256, 0, stream>>>(ffh, WmoT, bmo + i * DMM, nullptr, h, lam2 + i * DMM,
                                           (i == 2) ? (float*)d_out : nullptr, DFF, DMM);
    }
}